// Round 5
// baseline (1210.461 us; speedup 1.0000x reference)
//
#include <hip/hip_runtime.h>
#include <hip/hip_cooperative_groups.h>
#include <hip/hip_fp16.h>
#include <math.h>

#define HH 512
#define WW 512
#define BB 4
#define NPIX (BB * HH * WW)

#define T_H 16
#define T_W 64
#define GX (WW / T_W)       // 8
#define GY (HH / T_H)       // 32
#define I_ROWS (T_H + 4)    // 20 rows: h0-2 .. h0+T_H+1
#define I_COLS (T_W + 4)    // 68 cols
#define S_ROWS (T_H + 3)    // 19 rows: h0-1 .. h0+T_H+1
#define S_COLS (T_W + 2)    // 66 cols
#define LST 68              // LDS row stride (f32)

constexpr float TAUf   = 0.01f;
constexpr float RHOf   = 1.99f;
constexpr float SIGMAf = (float)(1.0 / 0.01 / 72.0);
constexpr float INV_1P_TAU = (float)(1.0 / 1.01);

struct h4 { __half x, y, z, w; };

__device__ __forceinline__ h4 ldu4(const __half* __restrict__ u, int idx) {
    return *(const h4*)(u + 4 * (size_t)idx);
}

__global__ __launch_bounds__(256, 4) void fused_all(
    const float* __restrict__ y, const int* __restrict__ ths_p,
    __half* x2a, __half* r2a, __half* ua,
    __half* x2b, __half* r2b, __half* ub,
    float* __restrict__ xout)
{
    cooperative_groups::grid_group grid = cooperative_groups::this_grid();

    __shared__ float i0s[I_ROWS][LST], i1s[I_ROWS][LST];
    __shared__ float ss[S_ROWS][LST], t0s[S_ROWS][LST], t1s[S_ROWS][LST];

    const int tid = threadIdx.x;
    const int bx = blockIdx.x, by = blockIdx.y;
    const int w0 = bx * T_W, h0 = by * T_H;
    const int boff = blockIdx.z * (HH * WW);
    const bool interior = (bx > 0) && (bx < GX - 1) && (by > 0) && (by < GY - 1);

    const float ths = (float)ths_p[0];
    const float inv_taulam1 = 1.0f / (TAUf * (ths * 0.1f));
    const float inv_lam2 = 1.0f / (ths * 0.15f);

    // ---- phase 0: i = eps2_adj(u_in) over I_ROWS x I_COLS -> LDS ----
    auto phase0 = [&](const __half* __restrict__ u_in) {
        if (interior) {
            for (int p = tid; p < I_ROWS * I_COLS; p += 256) {
                int ih = p / I_COLS, iw = p - ih * I_COLS;
                int idx = boff + (h0 - 2 + ih) * WW + (w0 - 2 + iw);
                h4 uc = ldu4(u_in, idx);
                h4 ud = ldu4(u_in, idx + WW);
                h4 ur = ldu4(u_in, idx + 1);
                h4 uu = ldu4(u_in, idx - WW);
                i0s[ih][iw] = __half2float(uc.x) - __half2float(ud.x)
                            - __half2float(ur.y) + __half2float(uc.y);
                i1s[ih][iw] = __half2float(uc.z) - __half2float(ur.z)
                            - __half2float(uc.w) + __half2float(uu.w);
            }
        } else {
            for (int p = tid; p < I_ROWS * I_COLS; p += 256) {
                int ih = p / I_COLS, iw = p - ih * I_COLS;
                int h = h0 - 2 + ih, w = w0 - 2 + iw;
                float i0 = 0.f, i1 = 0.f;
                if (h >= 0 && h < HH && w >= 0 && w < WW) {
                    int idx = boff + h * WW + w;
                    h4 uc = ldu4(u_in, idx);
                    float u0c = __half2float(uc.x), u1c = __half2float(uc.y);
                    float u2c = __half2float(uc.z), u3c = __half2float(uc.w);
                    float u0d = 0.f, u1r = 0.f, u2r = 0.f, u3u = 0.f;
                    if (h < HH - 1) u0d = __half2float(ldu4(u_in, idx + WW).x);
                    if (w < WW - 1) { h4 ur = ldu4(u_in, idx + 1);
                                      u1r = __half2float(ur.y); u2r = __half2float(ur.z); }
                    if (h >= 1)     u3u = __half2float(ldu4(u_in, idx - WW).w);
                    i0 = u0c - u0d - u1r + ((w >= 1) ? u1c : 0.f);
                    i1 = u2c - u2r - ((h < HH - 1) ? u3c : 0.f) + u3u;
                }
                i0s[ih][iw] = i0;
                i1s[ih][iw] = i1;
            }
        }
    };

    // ---- phase 2: dual update on 16x64 interior (u_in==nullptr means u=0) ----
    auto phase2 = [&](const __half* __restrict__ u_in, __half* __restrict__ u_out) {
        #pragma unroll
        for (int k = 0; k < 4; ++k) {
            int lh = (tid >> 6) + (k << 2);
            int lw = tid & 63;
            int h = h0 + lh, w = w0 + lw;
            int idx = boff + h * WW + w;
            int sh = lh + 1, sw = lw + 1;

            float G0, G1, G2, G3;
            if (interior) {
                float scc = ss[sh][sw];
                float scl = ss[sh][sw - 1];
                float sdn = ss[sh + 1][sw];
                float v0c = ss[sh][sw + 1] - scc - t0s[sh][sw];
                float v1c = sdn - scc - t1s[sh][sw];
                float v0u = ss[sh - 1][sw + 1] - ss[sh - 1][sw] - t0s[sh - 1][sw];
                float v0l = scc - scl - t0s[sh][sw - 1];
                float v1l = ss[sh + 1][sw - 1] - scl - t1s[sh][sw - 1];
                float v1d = ss[sh + 2][sw] - sdn - t1s[sh + 1][sw];
                G0 = v0c - v0u;
                G1 = v0c - v0l;
                G2 = v1c - v1l;
                G3 = v1d - v1c;
            } else {
                auto v0f = [&](int sh2, int sw2, int w2) -> float {
                    float d = (w2 < WW - 1) ? (ss[sh2][sw2 + 1] - ss[sh2][sw2]) : 0.f;
                    return d - t0s[sh2][sw2];
                };
                auto v1f = [&](int sh2, int sw2, int h2) -> float {
                    float d = (h2 < HH - 1) ? (ss[sh2 + 1][sw2] - ss[sh2][sw2]) : 0.f;
                    return d - t1s[sh2][sw2];
                };
                float v0c = v0f(sh, sw, w);
                float v1c = v1f(sh, sw, h);
                G0 = v0c - ((h >= 1) ? v0f(sh - 1, sw, w) : 0.f);
                G1 = (w >= 1) ? (v0c - v0f(sh, sw - 1, w - 1)) : 0.f;
                G2 = v1c - ((w >= 1) ? v1f(sh, sw - 1, h) : 0.f);
                G3 = (h < HH - 1) ? (v1f(sh + 1, sw, h + 1) - v1c) : 0.f;
            }

            float u0v = 0.f, u1v = 0.f, u2v = 0.f, u3v = 0.f;
            if (u_in) {
                h4 uc = ldu4(u_in, idx);
                u0v = __half2float(uc.x); u1v = __half2float(uc.y);
                u2v = __half2float(uc.z); u3v = __half2float(uc.w);
            }
            float uu0 = u0v + SIGMAf * G0;
            float uu1 = u1v + SIGMAf * G1;
            float uu2 = u2v + SIGMAf * G2;
            float uu3 = u3v + SIGMAf * G3;

            float mag = sqrtf(uu0 * uu0 + uu1 * uu1 + uu2 * uu2 + uu3 * uu3) * inv_lam2;
            float uinv = 1.0f / fmaxf(mag, 1.0f);

            h4 un;
            un.x = __float2half(u0v + RHOf * (uu0 * uinv - u0v));
            un.y = __float2half(u1v + RHOf * (uu1 * uinv - u1v));
            un.z = __float2half(u2v + RHOf * (uu2 * uinv - u2v));
            un.w = __float2half(u3v + RHOf * (uu3 * uinv - u3v));
            *(h4*)(u_out + 4 * (size_t)idx) = un;
        }
    };

    // ================= iter 0 (analytic: x=y, r=0) =================
    for (int p = tid; p < S_ROWS * S_COLS; p += 256) {
        int sh = p / S_COLS, sw = p - sh * S_COLS;
        int h = h0 - 1 + sh, w = w0 - 1 + sw;
        float sv = 0.f;
        if (h >= 0 && h < HH && w >= 0 && w < WW) {
            int idx = boff + h * WW + w;
            float yv = y[idx];
            sv = yv;
            if (sh >= 1 && sh <= T_H && sw >= 1 && sw <= T_W) {
                x2b[idx] = __float2half(yv);
                *(__half2*)(r2b + 2 * (size_t)idx) =
                    __halves2half2(__float2half(0.f), __float2half(0.f));
            }
        }
        ss[sh][sw]  = sv;
        t0s[sh][sw] = 0.f;
        t1s[sh][sw] = 0.f;
    }
    __syncthreads();
    phase2(nullptr, ub);
    grid.sync();

    __half *ix2 = x2b, *ir2 = r2b, *iu = ub;
    __half *ox2 = x2a, *or2 = r2a, *ou = ua;

    // ================= iters 1..8 =================
    for (int it = 1; it <= 8; ++it) {
        phase0(iu);
        __syncthreads();

        for (int p = tid; p < S_ROWS * S_COLS; p += 256) {
            int sh = p / S_COLS, sw = p - sh * S_COLS;
            int h = h0 - 1 + sh, w = w0 - 1 + sw;
            float sv = 0.f, t0v = 0.f, t1v = 0.f;
            bool in_img = interior || (h >= 0 && h < HH && w >= 0 && w < WW);
            if (in_img) {
                int idx = boff + h * WW + w;
                float i0c = i0s[sh + 1][sw + 1], i0l = i0s[sh + 1][sw];
                float i1c = i1s[sh + 1][sw + 1], i1u = i1s[sh][sw + 1];
                float na;
                if (interior) {
                    na = TAUf * (i0l - i0c + i1u - i1c);
                } else {
                    na = 0.f;
                    if (w < WW - 1) na -= TAUf * i0c;
                    if (w >= 1)     na += TAUf * i0l;
                    if (h < HH - 1) na -= TAUf * i1c;
                    if (h >= 1)     na += TAUf * i1u;
                }
                float yv  = y[idx];
                float x2v = __half2float(ix2[idx]);
                float x = (x2v - na + TAUf * yv) * INV_1P_TAU;
                __half2 r2v2 = *(const __half2*)(ir2 + 2 * (size_t)idx);
                float r20v = __half2float(r2v2.x);
                float r21v = __half2float(r2v2.y);
                float rr0 = r20v + TAUf * i0c;
                float rr1 = r21v + TAUf * i1c;
                float mag = sqrtf(rr0 * rr0 + rr1 * rr1) * inv_taulam1;
                float rinv = 1.0f / fmaxf(mag, 1.0f);
                float r0 = rr0 - rr0 * rinv;
                float r1 = rr1 - rr1 * rinv;
                sv  = 2.0f * x  - x2v;
                t0v = 2.0f * r0 - r20v;
                t1v = 2.0f * r1 - r21v;
                if (sh >= 1 && sh <= T_H && sw >= 1 && sw <= T_W) {
                    ox2[idx] = __float2half(x2v + RHOf * (x - x2v));
                    *(__half2*)(or2 + 2 * (size_t)idx) = __halves2half2(
                        __float2half(r20v + RHOf * (r0 - r20v)),
                        __float2half(r21v + RHOf * (r1 - r21v)));
                }
            }
            ss[sh][sw]  = sv;
            t0s[sh][sw] = t0v;
            t1s[sh][sw] = t1v;
        }
        __syncthreads();

        phase2(iu, ou);
        grid.sync();

        __half* t;
        t = ix2; ix2 = ox2; ox2 = t;
        t = ir2; ir2 = or2; or2 = t;
        t = iu;  iu  = ou;  ou  = t;
    }

    // ================= iter 9 (last: only x) =================
    phase0(iu);
    __syncthreads();

    #pragma unroll
    for (int k = 0; k < 4; ++k) {
        int lh = (tid >> 6) + (k << 2);
        int lw = tid & 63;
        int h = h0 + lh, w = w0 + lw;
        int idx = boff + h * WW + w;
        int sh = lh + 1, sw = lw + 1;
        float i0c = i0s[sh + 1][sw + 1], i0l = i0s[sh + 1][sw];
        float i1c = i1s[sh + 1][sw + 1], i1u = i1s[sh][sw + 1];
        float na;
        if (interior) {
            na = TAUf * (i0l - i0c + i1u - i1c);
        } else {
            na = 0.f;
            if (w < WW - 1) na -= TAUf * i0c;
            if (w >= 1)     na += TAUf * i0l;
            if (h < HH - 1) na -= TAUf * i1c;
            if (h >= 1)     na += TAUf * i1u;
        }
        float yv  = y[idx];
        float x2v = __half2float(ix2[idx]);
        float x = (x2v - na + TAUf * yv) * INV_1P_TAU;
        xout[idx] = x2v + RHOf * (x - x2v);
    }
}

extern "C" void kernel_launch(void* const* d_in, const int* in_sizes, int n_in,
                              void* d_out, int out_size, void* d_ws, size_t ws_size,
                              hipStream_t stream)
{
    const float* y   = (const float*)d_in[0];
    const int*   ths = (const int*)d_in[1];
    __half* ws = (__half*)d_ws;

    __half* x2a = ws;
    __half* r2a = ws + (size_t)NPIX;
    __half* ua  = ws + (size_t)3 * NPIX;
    __half* x2b = ws + (size_t)7 * NPIX;
    __half* r2b = ws + (size_t)8 * NPIX;
    __half* ub  = ws + (size_t)10 * NPIX;
    float*  xout = (float*)d_out;

    void* args[] = {
        (void*)&y, (void*)&ths,
        (void*)&x2a, (void*)&r2a, (void*)&ua,
        (void*)&x2b, (void*)&r2b, (void*)&ub,
        (void*)&xout
    };

    hipLaunchCooperativeKernel((const void*)fused_all,
                               dim3(GX, GY, BB), dim3(256),
                               args, 0, stream);
}

// Round 6
// 271.891 us; speedup vs baseline: 4.4520x; 4.4520x over previous
//
#include <hip/hip_runtime.h>
#include <hip/hip_fp16.h>
#include <math.h>

#define HH 512
#define WW 512
#define BB 4
#define NPIX (BB * HH * WW)

#define T_H 16
#define T_W 64
#define GX 8
#define GY 32

// Stage regions (origins relative to tile corner (h0,w0)):
// A:  i   origin (-5,-4) dims 26x71 stride 72
// B:  s,t origin (-4,-3) dims 25x70 stride 72 ; x2p/r2p origin (-1,-1) 19x66 stride 68
// C:  u'  origin (-3,-2) dims 22x68 stride 68 (fp16)
// D1: i'  origin (-2,-2) dims 20x67 (reuse i buffers, stride 72)
// D2: s',t' origin (-1,-1) dims 19x66 (reuse s,t buffers, stride 72)
// E:  u'' on 16x64 tile
#define IA_R 26
#define IA_C 71
#define IA_S 72
#define SB_R 25
#define SB_C 70
#define SB_S 72
#define XP_R 19
#define XP_C 66
#define XP_S 68
#define UC_R 22
#define UC_C 68
#define UC_S 68
#define ID_R 20
#define ID_C 67
#define SD_R 19
#define SD_C 66

constexpr float TAUf   = 0.01f;
constexpr float RHOf   = 1.99f;
constexpr float SIGMAf = (float)(1.0 / 0.01 / 72.0);
constexpr float INV_1P_TAU = (float)(1.0 / 1.01);

struct h4 { __half x, y, z, w; };

__device__ __forceinline__ h4 ldu4(const __half* __restrict__ u, int idx) {
    return *(const h4*)(u + 4 * (size_t)idx);
}
__device__ __forceinline__ float c(__half v) { return __half2float(v); }

// MODE: 0 = first pair (iters 0,1: analytic iter0), 1 = mid pair, 2 = last pair (iters 8,9)
template <int MODE>
__global__ __launch_bounds__(256) void fused_pair(
    const float* __restrict__ y, const int* __restrict__ ths_p,
    const __half* __restrict__ x2_in, const __half* __restrict__ r2_in,
    const __half* __restrict__ u_in,
    __half* __restrict__ x2_out, __half* __restrict__ r2_out,
    __half* __restrict__ u_out, float* __restrict__ xout)
{
    __shared__ float i0s[IA_R * IA_S], i1s[IA_R * IA_S];
    __shared__ float ss[SB_R * SB_S], t0s[SB_R * SB_S], t1s[SB_R * SB_S];
    __shared__ float x2p[XP_R * XP_S], r20p[XP_R * XP_S], r21p[XP_R * XP_S];
    __shared__ __half up0[UC_R * UC_S], up1[UC_R * UC_S],
                      up2[UC_R * UC_S], up3[UC_R * UC_S];

    const int tid = threadIdx.x;
    const int bx = blockIdx.x, by = blockIdx.y;
    const int w0 = bx * T_W, h0 = by * T_H;
    const int boff = blockIdx.z * (HH * WW);
    const bool interior = (bx >= 1) && (bx <= 6) && (by >= 1) && (by <= 30);

    const float ths = (float)ths_p[0];
    const float inv_taulam1 = 1.0f / (TAUf * (ths * 0.1f));
    const float inv_lam2 = 1.0f / (ths * 0.15f);

    // ================= stage A: i = eps2_adj(u^n) =================
    if (MODE != 0) {
        if (interior) {
            for (int p = tid; p < IA_R * IA_C; p += 256) {
                int ih = p / IA_C, iw = p - ih * IA_C;
                int idx = boff + (h0 - 5 + ih) * WW + (w0 - 4 + iw);
                h4 uc = ldu4(u_in, idx);
                h4 ud = ldu4(u_in, idx + WW);
                h4 ur = ldu4(u_in, idx + 1);
                h4 uu = ldu4(u_in, idx - WW);
                i0s[ih * IA_S + iw] = c(uc.x) - c(ud.x) - c(ur.y) + c(uc.y);
                i1s[ih * IA_S + iw] = c(uc.z) - c(ur.z) - c(uc.w) + c(uu.w);
            }
        } else {
            for (int p = tid; p < IA_R * IA_C; p += 256) {
                int ih = p / IA_C, iw = p - ih * IA_C;
                int h = h0 - 5 + ih, w = w0 - 4 + iw;
                float i0 = 0.f, i1 = 0.f;
                if (h >= 0 && h < HH && w >= 0 && w < WW) {
                    int idx = boff + h * WW + w;
                    h4 uc = ldu4(u_in, idx);
                    float u0c = c(uc.x), u1c = c(uc.y), u2c = c(uc.z), u3c = c(uc.w);
                    float u0d = 0.f, u1r = 0.f, u2r = 0.f, u3u = 0.f;
                    if (h < HH - 1) u0d = c(ldu4(u_in, idx + WW).x);
                    if (w < WW - 1) { h4 ur = ldu4(u_in, idx + 1);
                                      u1r = c(ur.y); u2r = c(ur.z); }
                    if (h >= 1)     u3u = c(ldu4(u_in, idx - WW).w);
                    i0 = u0c - u0d - u1r + ((w >= 1) ? u1c : 0.f);
                    i1 = u2c - u2r - ((h < HH - 1) ? u3c : 0.f) + u3u;
                }
                i0s[ih * IA_S + iw] = i0;
                i1s[ih * IA_S + iw] = i1;
            }
        }
        __syncthreads();
    }

    // ================= stage B: s,t (iter n), stash x2',r2' =================
    for (int p = tid; p < SB_R * SB_C; p += 256) {
        int sh = p / SB_C, sw = p - sh * SB_C;
        int h = h0 - 4 + sh, w = w0 - 3 + sw;
        float sv = 0.f, t0v = 0.f, t1v = 0.f;
        bool in_img = interior || (h >= 0 && h < HH && w >= 0 && w < WW);
        if (in_img) {
            int idx = boff + h * WW + w;
            if (MODE == 0) {
                // iter 0: x = y, r = 0
                float yv = y[idx];
                sv = yv;
                if (sh >= 3 && sh < 3 + XP_R && sw >= 2 && sw < 2 + XP_C) {
                    x2p[(sh - 3) * XP_S + (sw - 2)]  = yv;
                    r20p[(sh - 3) * XP_S + (sw - 2)] = 0.f;
                    r21p[(sh - 3) * XP_S + (sw - 2)] = 0.f;
                }
            } else {
                float i0c = i0s[(sh + 1) * IA_S + sw + 1];
                float i0l = i0s[(sh + 1) * IA_S + sw];
                float i1c = i1s[(sh + 1) * IA_S + sw + 1];
                float i1u = i1s[sh * IA_S + sw + 1];
                float na;
                if (interior) {
                    na = TAUf * (i0l - i0c + i1u - i1c);
                } else {
                    na = 0.f;
                    if (w < WW - 1) na -= TAUf * i0c;
                    if (w >= 1)     na += TAUf * i0l;
                    if (h < HH - 1) na -= TAUf * i1c;
                    if (h >= 1)     na += TAUf * i1u;
                }
                float yv  = y[idx];
                float x2v = c(x2_in[idx]);
                float x = (x2v - na + TAUf * yv) * INV_1P_TAU;
                __half2 r2v2 = *(const __half2*)(r2_in + 2 * (size_t)idx);
                float r20v = c(r2v2.x), r21v = c(r2v2.y);
                float rr0 = r20v + TAUf * i0c;
                float rr1 = r21v + TAUf * i1c;
                float mag = sqrtf(rr0 * rr0 + rr1 * rr1) * inv_taulam1;
                float rinv = 1.0f / fmaxf(mag, 1.0f);
                float r0 = rr0 - rr0 * rinv;
                float r1 = rr1 - rr1 * rinv;
                sv  = 2.0f * x  - x2v;
                t0v = 2.0f * r0 - r20v;
                t1v = 2.0f * r1 - r21v;
                if (sh >= 3 && sh < 3 + XP_R && sw >= 2 && sw < 2 + XP_C) {
                    x2p[(sh - 3) * XP_S + (sw - 2)]  = x2v + RHOf * (x - x2v);
                    r20p[(sh - 3) * XP_S + (sw - 2)] = r20v + RHOf * (r0 - r20v);
                    r21p[(sh - 3) * XP_S + (sw - 2)] = r21v + RHOf * (r1 - r21v);
                }
            }
        }
        ss[sh * SB_S + sw]  = sv;
        t0s[sh * SB_S + sw] = t0v;
        t1s[sh * SB_S + sw] = t1v;
    }
    __syncthreads();

    // ================= stage C: u' (iter n dual update) -> LDS fp16 =================
    for (int p = tid; p < UC_R * UC_C; p += 256) {
        int ch = p / UC_C, cw = p - ch * UC_C;
        int h = h0 - 3 + ch, w = w0 - 2 + cw;
        float n0 = 0.f, n1 = 0.f, n2 = 0.f, n3 = 0.f;
        bool in_img = interior || (h >= 0 && h < HH && w >= 0 && w < WW);
        if (in_img) {
            int sh = ch + 1, sw = cw + 1;
            float G0, G1, G2, G3;
            if (interior) {
                float scc = ss[sh * SB_S + sw];
                float scl = ss[sh * SB_S + sw - 1];
                float sdn = ss[(sh + 1) * SB_S + sw];
                float v0c = ss[sh * SB_S + sw + 1] - scc - t0s[sh * SB_S + sw];
                float v1c = sdn - scc - t1s[sh * SB_S + sw];
                float v0u = ss[(sh - 1) * SB_S + sw + 1] - ss[(sh - 1) * SB_S + sw]
                          - t0s[(sh - 1) * SB_S + sw];
                float v0l = scc - scl - t0s[sh * SB_S + sw - 1];
                float v1l = ss[(sh + 1) * SB_S + sw - 1] - scl - t1s[sh * SB_S + sw - 1];
                float v1d = ss[(sh + 2) * SB_S + sw] - sdn - t1s[(sh + 1) * SB_S + sw];
                G0 = v0c - v0u;
                G1 = v0c - v0l;
                G2 = v1c - v1l;
                G3 = v1d - v1c;
            } else {
                auto v0f = [&](int r2, int c2, int wq) -> float {
                    float d = (wq < WW - 1) ? (ss[r2 * SB_S + c2 + 1] - ss[r2 * SB_S + c2]) : 0.f;
                    return d - t0s[r2 * SB_S + c2];
                };
                auto v1f = [&](int r2, int c2, int hq) -> float {
                    float d = (hq < HH - 1) ? (ss[(r2 + 1) * SB_S + c2] - ss[r2 * SB_S + c2]) : 0.f;
                    return d - t1s[r2 * SB_S + c2];
                };
                float v0c = v0f(sh, sw, w);
                float v1c = v1f(sh, sw, h);
                G0 = v0c - ((h >= 1) ? v0f(sh - 1, sw, w) : 0.f);
                G1 = (w >= 1) ? (v0c - v0f(sh, sw - 1, w - 1)) : 0.f;
                G2 = v1c - ((w >= 1) ? v1f(sh, sw - 1, h) : 0.f);
                G3 = (h < HH - 1) ? (v1f(sh + 1, sw, h + 1) - v1c) : 0.f;
            }
            float u0v = 0.f, u1v = 0.f, u2v = 0.f, u3v = 0.f;
            if (MODE != 0) {
                h4 uc = ldu4(u_in, boff + h * WW + w);
                u0v = c(uc.x); u1v = c(uc.y); u2v = c(uc.z); u3v = c(uc.w);
            }
            float uu0 = u0v + SIGMAf * G0;
            float uu1 = u1v + SIGMAf * G1;
            float uu2 = u2v + SIGMAf * G2;
            float uu3 = u3v + SIGMAf * G3;
            float mag = sqrtf(uu0 * uu0 + uu1 * uu1 + uu2 * uu2 + uu3 * uu3) * inv_lam2;
            float uinv = 1.0f / fmaxf(mag, 1.0f);
            n0 = u0v + RHOf * (uu0 * uinv - u0v);
            n1 = u1v + RHOf * (uu1 * uinv - u1v);
            n2 = u2v + RHOf * (uu2 * uinv - u2v);
            n3 = u3v + RHOf * (uu3 * uinv - u3v);
        }
        up0[ch * UC_S + cw] = __float2half(n0);
        up1[ch * UC_S + cw] = __float2half(n1);
        up2[ch * UC_S + cw] = __float2half(n2);
        up3[ch * UC_S + cw] = __float2half(n3);
    }
    __syncthreads();

    // ================= stage D1: i' = eps2_adj(u') from LDS =================
    for (int p = tid; p < ID_R * ID_C; p += 256) {
        int ih = p / ID_C, iw = p - ih * ID_C;
        int h = h0 - 2 + ih, w = w0 - 2 + iw;
        float i0 = 0.f, i1 = 0.f;
        bool in_img = interior || (h >= 0 && h < HH && w >= 0 && w < WW);
        if (in_img) {
            int cr = ih + 1, cc = iw;
            float u0c = c(up0[cr * UC_S + cc]);
            float u0d = c(up0[(cr + 1) * UC_S + cc]);
            float u1c = c(up1[cr * UC_S + cc]);
            float u1r = c(up1[cr * UC_S + cc + 1]);
            float u2c = c(up2[cr * UC_S + cc]);
            float u2r = c(up2[cr * UC_S + cc + 1]);
            float u3c = c(up3[cr * UC_S + cc]);
            float u3u = c(up3[(cr - 1) * UC_S + cc]);
            if (interior) {
                i0 = u0c - u0d - u1r + u1c;
                i1 = u2c - u2r - u3c + u3u;
            } else {
                i0 = u0c - ((h < HH - 1) ? u0d : 0.f) - ((w < WW - 1) ? u1r : 0.f)
                   + ((w >= 1) ? u1c : 0.f);
                i1 = u2c - ((w < WW - 1) ? u2r : 0.f) - ((h < HH - 1) ? u3c : 0.f)
                   + ((h >= 1) ? u3u : 0.f);
            }
        }
        i0s[ih * IA_S + iw] = i0;
        i1s[ih * IA_S + iw] = i1;
    }
    __syncthreads();

    // ================= stage D2: s',t' (iter n+1), write x2'',r2'' =================
    for (int p = tid; p < SD_R * SD_C; p += 256) {
        int sh2 = p / SD_C, sw2 = p - sh2 * SD_C;
        int h = h0 - 1 + sh2, w = w0 - 1 + sw2;
        float sv = 0.f, t0v = 0.f, t1v = 0.f;
        bool in_img = interior || (h >= 0 && h < HH && w >= 0 && w < WW);
        if (in_img) {
            int idx = boff + h * WW + w;
            float i0c = i0s[(sh2 + 1) * IA_S + sw2 + 1];
            float i0l = i0s[(sh2 + 1) * IA_S + sw2];
            float i1c = i1s[(sh2 + 1) * IA_S + sw2 + 1];
            float i1u = i1s[sh2 * IA_S + sw2 + 1];
            float na;
            if (interior) {
                na = TAUf * (i0l - i0c + i1u - i1c);
            } else {
                na = 0.f;
                if (w < WW - 1) na -= TAUf * i0c;
                if (w >= 1)     na += TAUf * i0l;
                if (h < HH - 1) na -= TAUf * i1c;
                if (h >= 1)     na += TAUf * i1u;
            }
            float yv  = y[idx];
            float x2v = x2p[sh2 * XP_S + sw2];
            float x = (x2v - na + TAUf * yv) * INV_1P_TAU;
            if (MODE == 2) {
                if (sh2 >= 1 && sh2 < 17 && sw2 >= 1 && sw2 < 65)
                    xout[idx] = x2v + RHOf * (x - x2v);
            } else {
                float r20v = r20p[sh2 * XP_S + sw2];
                float r21v = r21p[sh2 * XP_S + sw2];
                float rr0 = r20v + TAUf * i0c;
                float rr1 = r21v + TAUf * i1c;
                float mag = sqrtf(rr0 * rr0 + rr1 * rr1) * inv_taulam1;
                float rinv = 1.0f / fmaxf(mag, 1.0f);
                float r0 = rr0 - rr0 * rinv;
                float r1 = rr1 - rr1 * rinv;
                sv  = 2.0f * x  - x2v;
                t0v = 2.0f * r0 - r20v;
                t1v = 2.0f * r1 - r21v;
                if (sh2 >= 1 && sh2 < 17 && sw2 >= 1 && sw2 < 65) {
                    x2_out[idx] = __float2half(x2v + RHOf * (x - x2v));
                    *(__half2*)(r2_out + 2 * (size_t)idx) = __halves2half2(
                        __float2half(r20v + RHOf * (r0 - r20v)),
                        __float2half(r21v + RHOf * (r1 - r21v)));
                }
            }
        }
        if (MODE != 2) {
            ss[sh2 * SB_S + sw2]  = sv;
            t0s[sh2 * SB_S + sw2] = t0v;
            t1s[sh2 * SB_S + sw2] = t1v;
        }
    }
    if (MODE == 2) return;
    __syncthreads();

    // ================= stage E: u'' (iter n+1 dual) on 16x64 tile =================
    #pragma unroll
    for (int k = 0; k < 4; ++k) {
        int lh = (tid >> 6) + (k << 2);
        int lw = tid & 63;
        int h = h0 + lh, w = w0 + lw;
        int idx = boff + h * WW + w;
        int sh = lh + 1, sw = lw + 1;

        float G0, G1, G2, G3;
        if (interior) {
            float scc = ss[sh * SB_S + sw];
            float scl = ss[sh * SB_S + sw - 1];
            float sdn = ss[(sh + 1) * SB_S + sw];
            float v0c = ss[sh * SB_S + sw + 1] - scc - t0s[sh * SB_S + sw];
            float v1c = sdn - scc - t1s[sh * SB_S + sw];
            float v0u = ss[(sh - 1) * SB_S + sw + 1] - ss[(sh - 1) * SB_S + sw]
                      - t0s[(sh - 1) * SB_S + sw];
            float v0l = scc - scl - t0s[sh * SB_S + sw - 1];
            float v1l = ss[(sh + 1) * SB_S + sw - 1] - scl - t1s[sh * SB_S + sw - 1];
            float v1d = ss[(sh + 2) * SB_S + sw] - sdn - t1s[(sh + 1) * SB_S + sw];
            G0 = v0c - v0u;
            G1 = v0c - v0l;
            G2 = v1c - v1l;
            G3 = v1d - v1c;
        } else {
            auto v0f = [&](int r2, int c2, int wq) -> float {
                float d = (wq < WW - 1) ? (ss[r2 * SB_S + c2 + 1] - ss[r2 * SB_S + c2]) : 0.f;
                return d - t0s[r2 * SB_S + c2];
            };
            auto v1f = [&](int r2, int c2, int hq) -> float {
                float d = (hq < HH - 1) ? (ss[(r2 + 1) * SB_S + c2] - ss[r2 * SB_S + c2]) : 0.f;
                return d - t1s[r2 * SB_S + c2];
            };
            float v0c = v0f(sh, sw, w);
            float v1c = v1f(sh, sw, h);
            G0 = v0c - ((h >= 1) ? v0f(sh - 1, sw, w) : 0.f);
            G1 = (w >= 1) ? (v0c - v0f(sh, sw - 1, w - 1)) : 0.f;
            G2 = v1c - ((w >= 1) ? v1f(sh, sw - 1, h) : 0.f);
            G3 = (h < HH - 1) ? (v1f(sh + 1, sw, h + 1) - v1c) : 0.f;
        }

        int cr = lh + 3, cc = lw + 2;
        float u0v = c(up0[cr * UC_S + cc]);
        float u1v = c(up1[cr * UC_S + cc]);
        float u2v = c(up2[cr * UC_S + cc]);
        float u3v = c(up3[cr * UC_S + cc]);

        float uu0 = u0v + SIGMAf * G0;
        float uu1 = u1v + SIGMAf * G1;
        float uu2 = u2v + SIGMAf * G2;
        float uu3 = u3v + SIGMAf * G3;
        float mag = sqrtf(uu0 * uu0 + uu1 * uu1 + uu2 * uu2 + uu3 * uu3) * inv_lam2;
        float uinv = 1.0f / fmaxf(mag, 1.0f);

        h4 un;
        un.x = __float2half(u0v + RHOf * (uu0 * uinv - u0v));
        un.y = __float2half(u1v + RHOf * (uu1 * uinv - u1v));
        un.z = __float2half(u2v + RHOf * (uu2 * uinv - u2v));
        un.w = __float2half(u3v + RHOf * (uu3 * uinv - u3v));
        *(h4*)(u_out + 4 * (size_t)idx) = un;
    }
}

extern "C" void kernel_launch(void* const* d_in, const int* in_sizes, int n_in,
                              void* d_out, int out_size, void* d_ws, size_t ws_size,
                              hipStream_t stream)
{
    const float* y   = (const float*)d_in[0];
    const int*   ths = (const int*)d_in[1];
    __half* ws = (__half*)d_ws;

    // fp16 state ping-pong: x2 (NPIX), r2 interleaved (2*NPIX), u interleaved (4*NPIX)
    __half* Ax2 = ws;
    __half* Ar2 = ws + (size_t)NPIX;
    __half* Au  = ws + (size_t)3 * NPIX;
    __half* Bx2 = ws + (size_t)7 * NPIX;
    __half* Br2 = ws + (size_t)8 * NPIX;
    __half* Bu  = ws + (size_t)10 * NPIX;
    float*  xout = (float*)d_out;

    dim3 block(256);
    dim3 grid(GX, GY, BB);

    // K0: iters 0-1 (analytic start) -> B
    fused_pair<0><<<grid, block, 0, stream>>>(
        y, ths, Ax2, Ar2, Au, Bx2, Br2, Bu, nullptr);
    // K1: iters 2-3: B -> A
    fused_pair<1><<<grid, block, 0, stream>>>(
        y, ths, Bx2, Br2, Bu, Ax2, Ar2, Au, nullptr);
    // K2: iters 4-5: A -> B
    fused_pair<1><<<grid, block, 0, stream>>>(
        y, ths, Ax2, Ar2, Au, Bx2, Br2, Bu, nullptr);
    // K3: iters 6-7: B -> A
    fused_pair<1><<<grid, block, 0, stream>>>(
        y, ths, Bx2, Br2, Bu, Ax2, Ar2, Au, nullptr);
    // K4: iters 8-9: A -> d_out (x only)
    fused_pair<2><<<grid, block, 0, stream>>>(
        y, ths, Ax2, Ar2, Au, nullptr, nullptr, nullptr, xout);
}

// Round 7
// 271.536 us; speedup vs baseline: 4.4578x; 1.0013x over previous
//
#include <hip/hip_runtime.h>
#include <hip/hip_fp16.h>
#include <math.h>

#define HH 512
#define WW 512
#define BB 4
#define NPIX (BB * HH * WW)

#define T_H 16
#define T_W 64
#define GX 8
#define GY 32

// LDS region geometry (origins relative to tile corner (h0,w0)):
// A:  i   origin (-5,-4) 26x71  (half2, stride SI)
// B:  s,t origin (-4,-3) 25x70  (half / half2, stride SS); stash x2',r2' origin (-1,-1) 19x66
// C:  u'  origin (-3,-2) 22x68  (h4, stride SU)
// D1: i'  origin (-2,-2) 20x67  (reuse i)
// D2: s',t' origin (-1,-1) 19x66 (reuse s,t); writes x2'',r2'' (or xout) on 16x64 core
// E:  u'' on 16x64 core
#define SI 71
#define SS 71
#define SU 68
#define SX 66

constexpr float TAUf   = 0.01f;
constexpr float RHOf   = 1.99f;
constexpr float SIGMAf = (float)(1.0 / 0.01 / 72.0);
constexpr float INV_1P_TAU = (float)(1.0 / 1.01);

struct h4 { __half x, y, z, w; };

__device__ __forceinline__ h4 ldu4(const __half* __restrict__ u, int idx) {
    return *(const h4*)(u + 4 * (size_t)idx);
}
__device__ __forceinline__ float cf(__half v) { return __half2float(v); }

// MODE: 0 = iters 0,1 (analytic iter 0); 1 = mid pair; 2 = iters 8,9 (x-only out)
template <int MODE>
__global__ __launch_bounds__(256, 4) void fused_pair(
    const float* __restrict__ y, const int* __restrict__ ths_p,
    const __half* __restrict__ x2_in, const __half* __restrict__ r2_in,
    const __half* __restrict__ u_in,
    __half* __restrict__ x2_out, __half* __restrict__ r2_out,
    __half* __restrict__ u_out, float* __restrict__ xout)
{
    __shared__ __half2 i01[26 * SI];
    __shared__ __half  ssb[25 * SS];
    __shared__ __half2 ttb[25 * SS];
    __shared__ __half  x2p[19 * SX];
    __shared__ __half2 r2p[19 * SX];
    __shared__ h4      upb[22 * SU];

    const int tid  = threadIdx.x;
    const int lane = tid & 63;
    const int rg   = tid >> 6;            // wave id (wave-uniform)
    const int bx = blockIdx.x, by = blockIdx.y;
    const int w0 = bx * T_W, h0 = by * T_H;
    const int boff = blockIdx.z * (HH * WW);
    const bool interior = (bx >= 1) && (bx <= 6) && (by >= 1) && (by <= 30);

    const float ths = (float)ths_p[0];
    const float inv_taulam1 = 1.0f / (TAUf * (ths * 0.1f));
    const float inv_lam2 = 1.0f / (ths * 0.15f);

    // ---------------- stage A: i = eps2_adj(u^n) ----------------
    if (MODE != 0) {
        if (interior) {
            const int base = boff + (h0 - 5) * WW + (w0 - 4);
            auto bodyA = [&](int r, int cc) {
                int idx = base + r * WW + cc;
                h4 uc = ldu4(u_in, idx);
                h4 ud = ldu4(u_in, idx + WW);
                h4 ur = ldu4(u_in, idx + 1);
                h4 uu = ldu4(u_in, idx - WW);
                i01[r * SI + cc] = __floats2half2_rn(
                    cf(uc.x) - cf(ud.x) - cf(ur.y) + cf(uc.y),
                    cf(uc.z) - cf(ur.z) - cf(uc.w) + cf(uu.w));
            };
            for (int r = rg; r < 26; r += 4) { bodyA(r, lane); if (lane < 7) bodyA(r, 64 + lane); }
        } else {
            auto bodyA = [&](int r, int cc) {
                int h = h0 - 5 + r, w = w0 - 4 + cc;
                float i0 = 0.f, i1 = 0.f;
                if (h >= 0 && h < HH && w >= 0 && w < WW) {
                    int idx = boff + h * WW + w;
                    h4 uc = ldu4(u_in, idx);
                    float u0c = cf(uc.x), u1c = cf(uc.y), u2c = cf(uc.z), u3c = cf(uc.w);
                    float u0d = 0.f, u1r = 0.f, u2r = 0.f, u3u = 0.f;
                    if (h < HH - 1) u0d = cf(ldu4(u_in, idx + WW).x);
                    if (w < WW - 1) { h4 ur = ldu4(u_in, idx + 1);
                                      u1r = cf(ur.y); u2r = cf(ur.z); }
                    if (h >= 1)     u3u = cf(ldu4(u_in, idx - WW).w);
                    i0 = u0c - u0d - u1r + ((w >= 1) ? u1c : 0.f);
                    i1 = u2c - u2r - ((h < HH - 1) ? u3c : 0.f) + u3u;
                }
                i01[r * SI + cc] = __floats2half2_rn(i0, i1);
            };
            for (int r = rg; r < 26; r += 4) { bodyA(r, lane); if (lane < 7) bodyA(r, 64 + lane); }
        }
        __syncthreads();
    }

    // ---------------- stage B: s,t (iter n); stash x2',r2' ----------------
    {
        auto bodyB = [&](int r, int cc) {
            int h = h0 - 4 + r, w = w0 - 3 + cc;
            float sv = 0.f, t0v = 0.f, t1v = 0.f;
            bool in_img = interior || (h >= 0 && h < HH && w >= 0 && w < WW);
            if (in_img) {
                int idx = boff + h * WW + w;
                if (MODE == 0) {
                    float yv = y[idx];
                    sv = yv;
                    if (r >= 3 && r < 22 && cc >= 2 && cc < 68) {
                        x2p[(r - 3) * SX + (cc - 2)] = __float2half(yv);
                        r2p[(r - 3) * SX + (cc - 2)] = __floats2half2_rn(0.f, 0.f);
                    }
                } else {
                    __half2 ic = i01[(r + 1) * SI + cc + 1];
                    __half2 il = i01[(r + 1) * SI + cc];
                    __half2 iu = i01[r * SI + cc + 1];
                    float i0c = __low2float(ic), i1c = __high2float(ic);
                    float i0l = __low2float(il), i1u = __high2float(iu);
                    float na;
                    if (interior) {
                        na = TAUf * (i0l - i0c + i1u - i1c);
                    } else {
                        na = 0.f;
                        if (w < WW - 1) na -= TAUf * i0c;
                        if (w >= 1)     na += TAUf * i0l;
                        if (h < HH - 1) na -= TAUf * i1c;
                        if (h >= 1)     na += TAUf * i1u;
                    }
                    float yv  = y[idx];
                    float x2v = cf(x2_in[idx]);
                    float x = (x2v - na + TAUf * yv) * INV_1P_TAU;
                    __half2 rv = *(const __half2*)(r2_in + 2 * (size_t)idx);
                    float r20v = __low2float(rv), r21v = __high2float(rv);
                    float rr0 = r20v + TAUf * i0c;
                    float rr1 = r21v + TAUf * i1c;
                    float mag = sqrtf(rr0 * rr0 + rr1 * rr1) * inv_taulam1;
                    float rinv = 1.0f / fmaxf(mag, 1.0f);
                    float r0 = rr0 - rr0 * rinv;
                    float r1 = rr1 - rr1 * rinv;
                    sv  = 2.0f * x  - x2v;
                    t0v = 2.0f * r0 - r20v;
                    t1v = 2.0f * r1 - r21v;
                    if (r >= 3 && r < 22 && cc >= 2 && cc < 68) {
                        x2p[(r - 3) * SX + (cc - 2)] = __float2half(x2v + RHOf * (x - x2v));
                        r2p[(r - 3) * SX + (cc - 2)] = __floats2half2_rn(
                            r20v + RHOf * (r0 - r20v), r21v + RHOf * (r1 - r21v));
                    }
                }
            }
            ssb[r * SS + cc] = __float2half(sv);
            ttb[r * SS + cc] = __floats2half2_rn(t0v, t1v);
        };
        for (int r = rg; r < 25; r += 4) { bodyB(r, lane); if (lane < 6) bodyB(r, 64 + lane); }
    }
    __syncthreads();

    // ---------------- stage C: u' (iter n dual) -> LDS ----------------
    {
        auto bodyC = [&](int r, int cc) {
            int h = h0 - 3 + r, w = w0 - 2 + cc;
            float n0 = 0.f, n1 = 0.f, n2 = 0.f, n3 = 0.f;
            bool in_img = interior || (h >= 0 && h < HH && w >= 0 && w < WW);
            if (in_img) {
                int sh = r + 1, sw = cc + 1;
                float G0, G1, G2, G3;
                if (interior) {
                    float scc = cf(ssb[sh * SS + sw]);
                    float scl = cf(ssb[sh * SS + sw - 1]);
                    float sdn = cf(ssb[(sh + 1) * SS + sw]);
                    __half2 tc = ttb[sh * SS + sw];
                    __half2 tl = ttb[sh * SS + sw - 1];
                    float v0c = cf(ssb[sh * SS + sw + 1]) - scc - __low2float(tc);
                    float v1c = sdn - scc - __high2float(tc);
                    float v0u = cf(ssb[(sh - 1) * SS + sw + 1]) - cf(ssb[(sh - 1) * SS + sw])
                              - __low2float(ttb[(sh - 1) * SS + sw]);
                    float v0l = scc - scl - __low2float(tl);
                    float v1l = cf(ssb[(sh + 1) * SS + sw - 1]) - scl - __high2float(tl);
                    float v1d = cf(ssb[(sh + 2) * SS + sw]) - sdn
                              - __high2float(ttb[(sh + 1) * SS + sw]);
                    G0 = v0c - v0u;
                    G1 = v0c - v0l;
                    G2 = v1c - v1l;
                    G3 = v1d - v1c;
                } else {
                    auto v0f = [&](int r2, int c2, int wq) -> float {
                        float d = (wq < WW - 1) ? (cf(ssb[r2 * SS + c2 + 1]) - cf(ssb[r2 * SS + c2])) : 0.f;
                        return d - __low2float(ttb[r2 * SS + c2]);
                    };
                    auto v1f = [&](int r2, int c2, int hq) -> float {
                        float d = (hq < HH - 1) ? (cf(ssb[(r2 + 1) * SS + c2]) - cf(ssb[r2 * SS + c2])) : 0.f;
                        return d - __high2float(ttb[r2 * SS + c2]);
                    };
                    float v0c = v0f(sh, sw, w);
                    float v1c = v1f(sh, sw, h);
                    G0 = v0c - ((h >= 1) ? v0f(sh - 1, sw, w) : 0.f);
                    G1 = (w >= 1) ? (v0c - v0f(sh, sw - 1, w - 1)) : 0.f;
                    G2 = v1c - ((w >= 1) ? v1f(sh, sw - 1, h) : 0.f);
                    G3 = (h < HH - 1) ? (v1f(sh + 1, sw, h + 1) - v1c) : 0.f;
                }
                float u0v = 0.f, u1v = 0.f, u2v = 0.f, u3v = 0.f;
                if (MODE != 0) {
                    h4 uc = ldu4(u_in, boff + h * WW + w);
                    u0v = cf(uc.x); u1v = cf(uc.y); u2v = cf(uc.z); u3v = cf(uc.w);
                }
                float uu0 = u0v + SIGMAf * G0;
                float uu1 = u1v + SIGMAf * G1;
                float uu2 = u2v + SIGMAf * G2;
                float uu3 = u3v + SIGMAf * G3;
                float mag = sqrtf(uu0 * uu0 + uu1 * uu1 + uu2 * uu2 + uu3 * uu3) * inv_lam2;
                float uinv = 1.0f / fmaxf(mag, 1.0f);
                n0 = u0v + RHOf * (uu0 * uinv - u0v);
                n1 = u1v + RHOf * (uu1 * uinv - u1v);
                n2 = u2v + RHOf * (uu2 * uinv - u2v);
                n3 = u3v + RHOf * (uu3 * uinv - u3v);
            }
            h4 un;
            un.x = __float2half(n0); un.y = __float2half(n1);
            un.z = __float2half(n2); un.w = __float2half(n3);
            upb[r * SU + cc] = un;
        };
        for (int r = rg; r < 22; r += 4) { bodyC(r, lane); if (lane < 4) bodyC(r, 64 + lane); }
    }
    __syncthreads();

    // ---------------- stage D1: i' = eps2_adj(u') from LDS ----------------
    {
        auto bodyD1 = [&](int r, int cc) {
            int h = h0 - 2 + r, w = w0 - 2 + cc;
            float i0 = 0.f, i1 = 0.f;
            bool in_img = interior || (h >= 0 && h < HH && w >= 0 && w < WW);
            if (in_img) {
                int cr = r + 1;
                h4 uc = upb[cr * SU + cc];
                h4 ur = upb[cr * SU + cc + 1];
                h4 ud = upb[(cr + 1) * SU + cc];
                h4 uu = upb[(cr - 1) * SU + cc];
                float u0c = cf(uc.x), u1c = cf(uc.y), u2c = cf(uc.z), u3c = cf(uc.w);
                float u0d = cf(ud.x), u1r = cf(ur.y), u2r = cf(ur.z), u3u = cf(uu.w);
                if (interior) {
                    i0 = u0c - u0d - u1r + u1c;
                    i1 = u2c - u2r - u3c + u3u;
                } else {
                    i0 = u0c - ((h < HH - 1) ? u0d : 0.f) - ((w < WW - 1) ? u1r : 0.f)
                       + ((w >= 1) ? u1c : 0.f);
                    i1 = u2c - ((w < WW - 1) ? u2r : 0.f) - ((h < HH - 1) ? u3c : 0.f)
                       + ((h >= 1) ? u3u : 0.f);
                }
            }
            i01[r * SI + cc] = __floats2half2_rn(i0, i1);
        };
        for (int r = rg; r < 20; r += 4) { bodyD1(r, lane); if (lane < 3) bodyD1(r, 64 + lane); }
    }
    __syncthreads();

    // ---------------- stage D2: s',t' (iter n+1); write x2'',r2'' / xout ----------------
    {
        auto bodyD2 = [&](int r, int cc) {
            int h = h0 - 1 + r, w = w0 - 1 + cc;
            float sv = 0.f, t0v = 0.f, t1v = 0.f;
            bool in_img = interior || (h >= 0 && h < HH && w >= 0 && w < WW);
            if (in_img) {
                int idx = boff + h * WW + w;
                __half2 ic = i01[(r + 1) * SI + cc + 1];
                __half2 il = i01[(r + 1) * SI + cc];
                __half2 iu = i01[r * SI + cc + 1];
                float i0c = __low2float(ic), i1c = __high2float(ic);
                float i0l = __low2float(il), i1u = __high2float(iu);
                float na;
                if (interior) {
                    na = TAUf * (i0l - i0c + i1u - i1c);
                } else {
                    na = 0.f;
                    if (w < WW - 1) na -= TAUf * i0c;
                    if (w >= 1)     na += TAUf * i0l;
                    if (h < HH - 1) na -= TAUf * i1c;
                    if (h >= 1)     na += TAUf * i1u;
                }
                float yv  = y[idx];
                float x2v = cf(x2p[r * SX + cc]);
                float x = (x2v - na + TAUf * yv) * INV_1P_TAU;
                if (MODE == 2) {
                    if (r >= 1 && r < 17 && cc >= 1 && cc < 65)
                        xout[idx] = x2v + RHOf * (x - x2v);
                } else {
                    __half2 rv = r2p[r * SX + cc];
                    float r20v = __low2float(rv), r21v = __high2float(rv);
                    float rr0 = r20v + TAUf * i0c;
                    float rr1 = r21v + TAUf * i1c;
                    float mag = sqrtf(rr0 * rr0 + rr1 * rr1) * inv_taulam1;
                    float rinv = 1.0f / fmaxf(mag, 1.0f);
                    float r0 = rr0 - rr0 * rinv;
                    float r1 = rr1 - rr1 * rinv;
                    sv  = 2.0f * x  - x2v;
                    t0v = 2.0f * r0 - r20v;
                    t1v = 2.0f * r1 - r21v;
                    if (r >= 1 && r < 17 && cc >= 1 && cc < 65) {
                        x2_out[idx] = __float2half(x2v + RHOf * (x - x2v));
                        *(__half2*)(r2_out + 2 * (size_t)idx) = __floats2half2_rn(
                            r20v + RHOf * (r0 - r20v), r21v + RHOf * (r1 - r21v));
                    }
                }
            }
            if (MODE != 2) {
                ssb[r * SS + cc] = __float2half(sv);
                ttb[r * SS + cc] = __floats2half2_rn(t0v, t1v);
            }
        };
        for (int r = rg; r < 19; r += 4) { bodyD2(r, lane); if (lane < 2) bodyD2(r, 64 + lane); }
    }
    if (MODE == 2) return;
    __syncthreads();

    // ---------------- stage E: u'' (iter n+1 dual) on 16x64 core ----------------
    #pragma unroll
    for (int k = 0; k < 4; ++k) {
        int lh = rg + (k << 2);
        int lw = lane;
        int h = h0 + lh, w = w0 + lw;
        int idx = boff + h * WW + w;
        int sh = lh + 1, sw = lw + 1;

        float G0, G1, G2, G3;
        if (interior) {
            float scc = cf(ssb[sh * SS + sw]);
            float scl = cf(ssb[sh * SS + sw - 1]);
            float sdn = cf(ssb[(sh + 1) * SS + sw]);
            __half2 tc = ttb[sh * SS + sw];
            __half2 tl = ttb[sh * SS + sw - 1];
            float v0c = cf(ssb[sh * SS + sw + 1]) - scc - __low2float(tc);
            float v1c = sdn - scc - __high2float(tc);
            float v0u = cf(ssb[(sh - 1) * SS + sw + 1]) - cf(ssb[(sh - 1) * SS + sw])
                      - __low2float(ttb[(sh - 1) * SS + sw]);
            float v0l = scc - scl - __low2float(tl);
            float v1l = cf(ssb[(sh + 1) * SS + sw - 1]) - scl - __high2float(tl);
            float v1d = cf(ssb[(sh + 2) * SS + sw]) - sdn
                      - __high2float(ttb[(sh + 1) * SS + sw]);
            G0 = v0c - v0u;
            G1 = v0c - v0l;
            G2 = v1c - v1l;
            G3 = v1d - v1c;
        } else {
            auto v0f = [&](int r2, int c2, int wq) -> float {
                float d = (wq < WW - 1) ? (cf(ssb[r2 * SS + c2 + 1]) - cf(ssb[r2 * SS + c2])) : 0.f;
                return d - __low2float(ttb[r2 * SS + c2]);
            };
            auto v1f = [&](int r2, int c2, int hq) -> float {
                float d = (hq < HH - 1) ? (cf(ssb[(r2 + 1) * SS + c2]) - cf(ssb[r2 * SS + c2])) : 0.f;
                return d - __high2float(ttb[r2 * SS + c2]);
            };
            float v0c = v0f(sh, sw, w);
            float v1c = v1f(sh, sw, h);
            G0 = v0c - ((h >= 1) ? v0f(sh - 1, sw, w) : 0.f);
            G1 = (w >= 1) ? (v0c - v0f(sh, sw - 1, w - 1)) : 0.f;
            G2 = v1c - ((w >= 1) ? v1f(sh, sw - 1, h) : 0.f);
            G3 = (h < HH - 1) ? (v1f(sh + 1, sw, h + 1) - v1c) : 0.f;
        }

        h4 upc = upb[(lh + 3) * SU + (lw + 2)];
        float u0v = cf(upc.x), u1v = cf(upc.y), u2v = cf(upc.z), u3v = cf(upc.w);

        float uu0 = u0v + SIGMAf * G0;
        float uu1 = u1v + SIGMAf * G1;
        float uu2 = u2v + SIGMAf * G2;
        float uu3 = u3v + SIGMAf * G3;
        float mag = sqrtf(uu0 * uu0 + uu1 * uu1 + uu2 * uu2 + uu3 * uu3) * inv_lam2;
        float uinv = 1.0f / fmaxf(mag, 1.0f);

        h4 un;
        un.x = __float2half(u0v + RHOf * (uu0 * uinv - u0v));
        un.y = __float2half(u1v + RHOf * (uu1 * uinv - u1v));
        un.z = __float2half(u2v + RHOf * (uu2 * uinv - u2v));
        un.w = __float2half(u3v + RHOf * (uu3 * uinv - u3v));
        *(h4*)(u_out + 4 * (size_t)idx) = un;
    }
}

extern "C" void kernel_launch(void* const* d_in, const int* in_sizes, int n_in,
                              void* d_out, int out_size, void* d_ws, size_t ws_size,
                              hipStream_t stream)
{
    const float* y   = (const float*)d_in[0];
    const int*   ths = (const int*)d_in[1];
    __half* ws = (__half*)d_ws;

    __half* Ax2 = ws;
    __half* Ar2 = ws + (size_t)NPIX;
    __half* Au  = ws + (size_t)3 * NPIX;
    __half* Bx2 = ws + (size_t)7 * NPIX;
    __half* Br2 = ws + (size_t)8 * NPIX;
    __half* Bu  = ws + (size_t)10 * NPIX;
    float*  xout = (float*)d_out;

    dim3 block(256);
    dim3 grid(GX, GY, BB);

    fused_pair<0><<<grid, block, 0, stream>>>(
        y, ths, Ax2, Ar2, Au, Bx2, Br2, Bu, nullptr);
    fused_pair<1><<<grid, block, 0, stream>>>(
        y, ths, Bx2, Br2, Bu, Ax2, Ar2, Au, nullptr);
    fused_pair<1><<<grid, block, 0, stream>>>(
        y, ths, Ax2, Ar2, Au, Bx2, Br2, Bu, nullptr);
    fused_pair<1><<<grid, block, 0, stream>>>(
        y, ths, Bx2, Br2, Bu, Ax2, Ar2, Au, nullptr);
    fused_pair<2><<<grid, block, 0, stream>>>(
        y, ths, Ax2, Ar2, Au, nullptr, nullptr, nullptr, xout);
}

// Round 8
// 211.634 us; speedup vs baseline: 5.7196x; 1.2830x over previous
//
#include <hip/hip_runtime.h>
#include <hip/hip_fp16.h>
#include <math.h>

#define HH 512
#define WW 512
#define BB 4
#define NPIX (BB * HH * WW)

#define HS 8                 // core rows per wave (must keep R0 % 4 == 0)
#define NSX 9                // strips: 9 x 60 core cols >= 512
#define NBAND (HH / HS)      // 64
#define NWAVES (NSX * NBAND * BB)   // 2304
#define NBLK (NWAVES / 4)           // 576

constexpr float TAUf   = 0.01f;
constexpr float RHOf   = 1.99f;
constexpr float SIGMAf = (float)(1.0 / 0.01 / 72.0);
constexpr float INV1PT = (float)(1.0 / 1.01);

__device__ __forceinline__ float cf(__half h) { return __half2float(h); }
__device__ __forceinline__ float SD(float v) { return __shfl_down(v, 1, 64); }  // lane+1
__device__ __forceinline__ float SUp(float v) { return __shfl_up(v, 1, 64); }   // lane-1

// MODE: 0 = iter 0 (analytic x=y,r=0,u=0); 1 = mid iter; 2 = last iter (x-only, f32 out)
template <int MODE>
__global__ __launch_bounds__(256) void sweep(
    const float* __restrict__ y, const int* __restrict__ ths_p,
    const __half* __restrict__ x2_in, const __half* __restrict__ r2_in,
    const __half* __restrict__ u_in,
    __half* __restrict__ x2_out, __half* __restrict__ r2_out,
    __half* __restrict__ u_out, float* __restrict__ xout)
{
    const int tid  = threadIdx.x;
    const int lane = tid & 63;
    const int wid  = blockIdx.x * 4 + (tid >> 6);
    const int sx   = wid % NSX;
    const int t2   = wid / NSX;
    const int band = t2 & (NBAND - 1);
    const int b    = t2 >> 6;                 // NBAND == 64
    const int R0   = band * HS;               // multiple of 8 -> ring slots are compile-time
    const int w    = sx * 60 - 2 + lane;
    const int boff = b * (HH * WW);
    const bool wok = ((unsigned)w) < (unsigned)WW;
    const float mA = (w >= 1 && w < WW) ? 1.f : 0.f;       // (w>=1) guard
    const float mB = (w >= 0 && w < WW - 1) ? 1.f : 0.f;   // (w<W-1) guard
    const bool cok = (lane >= 2) && (lane < 62) && (w < WW);

    const float ths     = (float)ths_p[0];
    const float inv_tl1 = 1.0f / (TAUf * (ths * 0.1f));
    const float inv_l2  = 1.0f / (ths * 0.15f);

    // register rings
    float uf0[4], uf1[4], uf2[4], uf3[4];     // u rows (unpacked f32)
    float i0r[2], i1r[2];                     // eps2_adj rows
    float sr[4], t0r[4], t1r[4];              // s, t rows
    #pragma unroll
    for (int q = 0; q < 4; ++q) { uf0[q]=uf1[q]=uf2[q]=uf3[q]=0.f; sr[q]=t0r[q]=t1r[q]=0.f; }
    i0r[0]=i0r[1]=i1r[0]=i1r[1]=0.f;

    auto uload = [&](int row) -> uint2 {
        uint2 z; z.x = 0u; z.y = 0u;
        if (((unsigned)row) < (unsigned)HH && wok)
            z = *(const uint2*)(u_in + 4 * (size_t)(boff + row * WW + w));
        return z;
    };
    auto unpk = [&](int slot, uint2 raw) {
        __half2 lo = *(reinterpret_cast<__half2*>(&raw.x));
        __half2 hi = *(reinterpret_cast<__half2*>(&raw.y));
        uf0[slot] = __low2float(lo); uf1[slot] = __high2float(lo);
        uf2[slot] = __low2float(hi); uf3[slot] = __high2float(hi);
    };
    // i(rr): islot, c = rr&3 (u row rr), d = (rr+1)&3, uu_ = (rr-1)&3
    auto compI = [&](int rr, int islot, int c, int d, int uu_) {
        if (((unsigned)rr) < (unsigned)HH) {
            float hD  = (rr < HH - 1) ? 1.f : 0.f;
            float u1c = uf1[c], u2c = uf2[c];
            i0r[islot] = uf0[c] - uf0[d] - SD(u1c) + mA * u1c;
            i1r[islot] = u2c - SD(u2c) - hD * uf3[c] + uf3[uu_];
        } else { i0r[islot] = 0.f; i1r[islot] = 0.f; }
    };

    if (MODE == 2) {
        // ---- last iter: only x output (f32) ----
        unpk(2, uload(R0 - 2));
        unpk(3, uload(R0 - 1));
        unpk(0, uload(R0));
        compI(R0 - 1, 1, 3, 0, 2);
        uint2 pu = uload(R0 + 1);
        float pyv, px2;
        {
            int row = R0; bool ok = wok;   // R0 in range always
            int idx = boff + row * WW + w;
            pyv = ok ? y[idx] : 0.f;
            px2 = ok ? cf(x2_in[idx]) : 0.f;
        }
        #pragma unroll
        for (int k = 0; k < HS; ++k) {
            const int rr = R0 + k;
            unpk((k + 1) & 3, pu);
            uint2 nu = uload(rr + 2);
            float yv = pyv, x2v = px2;
            if (k < HS - 1) {
                int row = rr + 1; bool ok = wok;
                int idx = boff + row * WW + w;
                pyv = ok ? y[idx] : 0.f;
                px2 = ok ? cf(x2_in[idx]) : 0.f;
            }
            compI(rr, k & 1, k & 3, (k + 1) & 3, (k + 3) & 3);
            float hD = (rr < HH - 1) ? 1.f : 0.f;
            float i0c = i0r[k & 1], i1c = i1r[k & 1], i1u = i1r[(k + 1) & 1];
            float i0l = SUp(i0c);
            float na = TAUf * (mA * i0l - mB * i0c + i1u - hD * i1c);
            float x = (x2v - na + TAUf * yv) * INV1PT;
            if (cok) xout[boff + rr * WW + w] = x2v + RHOf * (x - x2v);
            pu = nu;
        }
        return;
    }

    // s,t(rr); relax writes on core rows
    auto compS = [&](int rr, int ss_, int isc, int isp,
                     float yv, float x2v, float r20v, float r21v, bool coreRow) {
        if (((unsigned)rr) < (unsigned)HH) {
            if (MODE == 0) {
                sr[ss_] = yv; t0r[ss_] = 0.f; t1r[ss_] = 0.f;
                if (coreRow && cok) {
                    int idx = boff + rr * WW + w;
                    x2_out[idx] = __float2half(yv);
                    *(__half2*)(r2_out + 2 * (size_t)idx) = __floats2half2_rn(0.f, 0.f);
                }
            } else {
                float hD = (rr < HH - 1) ? 1.f : 0.f;
                float i0c = i0r[isc], i1c = i1r[isc], i1u = i1r[isp];
                float i0l = SUp(i0c);
                float na = TAUf * (mA * i0l - mB * i0c + i1u - hD * i1c);
                float x = (x2v - na + TAUf * yv) * INV1PT;
                float rr0 = r20v + TAUf * i0c;
                float rr1 = r21v + TAUf * i1c;
                float mag = sqrtf(rr0 * rr0 + rr1 * rr1) * inv_tl1;
                float rinv = 1.0f / fmaxf(mag, 1.0f);
                float r0 = rr0 - rr0 * rinv;
                float r1 = rr1 - rr1 * rinv;
                sr[ss_]  = 2.f * x  - x2v;
                t0r[ss_] = 2.f * r0 - r20v;
                t1r[ss_] = 2.f * r1 - r21v;
                if (coreRow && cok) {
                    int idx = boff + rr * WW + w;
                    x2_out[idx] = __float2half(x2v + RHOf * (x - x2v));
                    *(__half2*)(r2_out + 2 * (size_t)idx) = __floats2half2_rn(
                        r20v + RHOf * (r0 - r20v), r21v + RHOf * (r1 - r21v));
                }
            }
        } else { sr[ss_] = 0.f; t0r[ss_] = 0.f; t1r[ss_] = 0.f; }
    };

    // u'(ro): sc_=ro&3, sd_=(ro+1)&3, suu=(ro-1)&3, sdd_=(ro+2)&3, uslot=ro&3
    auto compU = [&](int ro, int sc_, int sd_, int suu, int sdd_, int uslot) {
        float hD  = (ro < HH - 1) ? 1.f : 0.f;
        float hD1 = (ro + 1 < HH - 1) ? 1.f : 0.f;
        float sc = sr[sc_], sd = sr[sd_], su = sr[suu], s2 = sr[sdd_];
        float t0c = t0r[sc_], t0u = t0r[suu];
        float t1c = t1r[sc_], t1d = t1r[sd_];
        float sc_p = SD(sc), su_p = SD(su);
        float sc_m = SUp(sc), sd_m = SUp(sd);
        float t0c_m = SUp(t0c), t1c_m = SUp(t1c);
        float v0c = mB * (sc_p - sc) - t0c;
        float v1c = hD * (sd - sc) - t1c;
        float v0u = mB * (su_p - su) - t0u;
        float v0l = (sc - sc_m) - t0c_m;
        float v1l = hD * (sd_m - sc_m) - t1c_m;
        float v1d = hD1 * (s2 - sd) - t1d;
        float G0 = v0c - v0u;
        float G1 = mA * (v0c - v0l);
        float G2 = v1c - mA * v1l;
        float G3 = hD * (v1d - v1c);
        float u0v, u1v, u2v, u3v;
        if (MODE == 0) { u0v = u1v = u2v = u3v = 0.f; }
        else { u0v = uf0[uslot]; u1v = uf1[uslot]; u2v = uf2[uslot]; u3v = uf3[uslot]; }
        float uu0 = u0v + SIGMAf * G0;
        float uu1 = u1v + SIGMAf * G1;
        float uu2 = u2v + SIGMAf * G2;
        float uu3 = u3v + SIGMAf * G3;
        float mag = sqrtf(uu0 * uu0 + uu1 * uu1 + uu2 * uu2 + uu3 * uu3) * inv_l2;
        float ui = 1.0f / fmaxf(mag, 1.0f);
        if (cok) {
            int idx = boff + ro * WW + w;
            __half2 lo = __floats2half2_rn(u0v + RHOf * (uu0 * ui - u0v),
                                           u1v + RHOf * (uu1 * ui - u1v));
            __half2 hi = __floats2half2_rn(u2v + RHOf * (uu2 * ui - u2v),
                                           u3v + RHOf * (uu3 * ui - u3v));
            uint2 st; st.x = *(unsigned*)&lo; st.y = *(unsigned*)&hi;
            *(uint2*)(u_out + 4 * (size_t)idx) = st;
        }
    };

    // ---- prologue ----
    uint2 pu; pu.x = 0u; pu.y = 0u;
    float pyv = 0.f, px2 = 0.f, pr0 = 0.f, pr1 = 0.f;
    if (MODE != 0) {
        unpk(1, uload(R0 - 3));
        unpk(2, uload(R0 - 2));
        unpk(3, uload(R0 - 1));
        compI(R0 - 2, 0, 2, 3, 1);
        pu = uload(R0);
    }
    {
        int row = R0 - 1; bool ok = (((unsigned)row) < (unsigned)HH) && wok;
        int idx = boff + row * WW + w;
        pyv = ok ? y[idx] : 0.f;
        if (MODE == 1) {
            px2 = ok ? cf(x2_in[idx]) : 0.f;
            __half2 rv = ok ? *(const __half2*)(r2_in + 2 * (size_t)idx)
                            : __floats2half2_rn(0.f, 0.f);
            pr0 = __low2float(rv); pr1 = __high2float(rv);
        }
    }

    // ---- main pipeline: rr = R0-1 .. R0+HS+1 ----
    #pragma unroll
    for (int k = 0; k < HS + 3; ++k) {
        const int rr = R0 - 1 + k;
        uint2 nu; nu.x = 0u; nu.y = 0u;
        if (MODE != 0) { unpk(k & 3, pu); nu = uload(rr + 2); }
        float yv = pyv, x2v = px2, r20v = pr0, r21v = pr1;
        if (k < HS + 2) {
            int row = rr + 1; bool ok = (((unsigned)row) < (unsigned)HH) && wok;
            int idx = boff + row * WW + w;
            pyv = ok ? y[idx] : 0.f;
            if (MODE == 1) {
                px2 = ok ? cf(x2_in[idx]) : 0.f;
                __half2 rv = ok ? *(const __half2*)(r2_in + 2 * (size_t)idx)
                                : __floats2half2_rn(0.f, 0.f);
                pr0 = __low2float(rv); pr1 = __high2float(rv);
            }
        }
        if (MODE != 0) compI(rr, (k + 1) & 1, (k + 3) & 3, k & 3, (k + 2) & 3);
        compS(rr, (k + 3) & 3, (k + 1) & 1, k & 1, yv, x2v, r20v, r21v,
              (k >= 1 && k <= HS));
        if (k >= 3) compU(R0 - 3 + k, (k + 1) & 3, (k + 2) & 3, k & 3, (k + 3) & 3,
                          (k + 1) & 3);
        if (MODE != 0) pu = nu;
    }
}

extern "C" void kernel_launch(void* const* d_in, const int* in_sizes, int n_in,
                              void* d_out, int out_size, void* d_ws, size_t ws_size,
                              hipStream_t stream)
{
    const float* y   = (const float*)d_in[0];
    const int*   ths = (const int*)d_in[1];
    __half* ws = (__half*)d_ws;

    __half* Ax2 = ws;
    __half* Ar2 = ws + (size_t)NPIX;
    __half* Au  = ws + (size_t)3 * NPIX;
    __half* Bx2 = ws + (size_t)7 * NPIX;
    __half* Br2 = ws + (size_t)8 * NPIX;
    __half* Bu  = ws + (size_t)10 * NPIX;
    float*  xout = (float*)d_out;

    dim3 block(256);
    dim3 grid(NBLK);

    // iter 0 (analytic) -> B
    sweep<0><<<grid, block, 0, stream>>>(y, ths, Ax2, Ar2, Au, Bx2, Br2, Bu, nullptr);
    // iters 1..8 alternate
    __half *ix2 = Bx2, *ir2 = Br2, *iu = Bu;
    __half *ox2 = Ax2, *or2 = Ar2, *ou = Au;
    for (int it = 1; it <= 8; ++it) {
        sweep<1><<<grid, block, 0, stream>>>(y, ths, ix2, ir2, iu, ox2, or2, ou, nullptr);
        __half* t;
        t = ix2; ix2 = ox2; ox2 = t;
        t = ir2; ir2 = or2; or2 = t;
        t = iu;  iu  = ou;  ou  = t;
    }
    // iter 9: x only -> d_out (state now in ix2/iu)
    sweep<2><<<grid, block, 0, stream>>>(y, ths, ix2, ir2, iu, nullptr, nullptr, nullptr, xout);
}

// Round 9
// 186.091 us; speedup vs baseline: 6.5047x; 1.1373x over previous
//
#include <hip/hip_runtime.h>
#include <hip/hip_fp16.h>
#include <math.h>

#define HH 512
#define WW 512
#define BB 4
#define NPIX (BB * HH * WW)

#define HS 4                 // core rows per wave (must keep R0 % 4 == 0)
#define NSX 9                // strips: 9 x 60 core cols >= 512
#define NBAND (HH / HS)      // 128
#define NWAVES (NSX * NBAND * BB)   // 4608
#define NBLK (NWAVES / 4)           // 1152

constexpr float TAUf   = 0.01f;
constexpr float RHOf   = 1.99f;
constexpr float SIGMAf = (float)(1.0 / 0.01 / 72.0);
constexpr float INV1PT = (float)(1.0 / 1.01);

__device__ __forceinline__ float cf(__half h) { return __half2float(h); }
__device__ __forceinline__ float SD(float v) { return __shfl_down(v, 1, 64); }  // lane+1
__device__ __forceinline__ float SUp(float v) { return __shfl_up(v, 1, 64); }   // lane-1

// MODE: 0 = iter 0 (analytic x=y,r=0,u=0); 1 = mid iter; 2 = last iter (x-only, f32 out)
template <int MODE>
__global__ __launch_bounds__(256) void sweep(
    const float* __restrict__ y, const int* __restrict__ ths_p,
    const __half* __restrict__ x2_in, const __half* __restrict__ r2_in,
    const __half* __restrict__ u_in,
    __half* __restrict__ x2_out, __half* __restrict__ r2_out,
    __half* __restrict__ u_out, float* __restrict__ xout)
{
    const int tid  = threadIdx.x;
    const int lane = tid & 63;
    const int wid  = blockIdx.x * 4 + (tid >> 6);
    const int sx   = wid % NSX;
    const int t2   = wid / NSX;
    const int band = t2 & (NBAND - 1);
    const int b    = t2 / NBAND;
    const int R0   = band * HS;               // multiple of 4 -> ring slots are compile-time
    const int w    = sx * 60 - 2 + lane;
    const int boff = b * (HH * WW);
    const bool wok = ((unsigned)w) < (unsigned)WW;
    const float mA = (w >= 1 && w < WW) ? 1.f : 0.f;       // (w>=1) guard
    const float mB = (w >= 0 && w < WW - 1) ? 1.f : 0.f;   // (w<W-1) guard
    const bool cok = (lane >= 2) && (lane < 62) && (w < WW);

    const float ths     = (float)ths_p[0];
    const float inv_tl1 = 1.0f / (TAUf * (ths * 0.1f));
    const float inv_l2  = 1.0f / (ths * 0.15f);

    // register rings
    float uf0[4], uf1[4], uf2[4], uf3[4];     // u rows (unpacked f32)
    float i0r[2], i1r[2];                     // eps2_adj rows
    float sr[4], t0r[4], t1r[4];              // s, t rows
    #pragma unroll
    for (int q = 0; q < 4; ++q) { uf0[q]=uf1[q]=uf2[q]=uf3[q]=0.f; sr[q]=t0r[q]=t1r[q]=0.f; }
    i0r[0]=i0r[1]=i1r[0]=i1r[1]=0.f;

    auto uload = [&](int row) -> uint2 {
        uint2 z; z.x = 0u; z.y = 0u;
        if (((unsigned)row) < (unsigned)HH && wok)
            z = *(const uint2*)(u_in + 4 * (size_t)(boff + row * WW + w));
        return z;
    };
    auto unpk = [&](int slot, uint2 raw) {
        __half2 lo = *(reinterpret_cast<__half2*>(&raw.x));
        __half2 hi = *(reinterpret_cast<__half2*>(&raw.y));
        uf0[slot] = __low2float(lo); uf1[slot] = __high2float(lo);
        uf2[slot] = __low2float(hi); uf3[slot] = __high2float(hi);
    };
    // i(rr): islot, c = rr&3 (u row rr), d = (rr+1)&3, uu_ = (rr-1)&3
    auto compI = [&](int rr, int islot, int c, int d, int uu_) {
        if (((unsigned)rr) < (unsigned)HH) {
            float hD  = (rr < HH - 1) ? 1.f : 0.f;
            float u1c = uf1[c], u2c = uf2[c];
            i0r[islot] = uf0[c] - uf0[d] - SD(u1c) + mA * u1c;
            i1r[islot] = u2c - SD(u2c) - hD * uf3[c] + uf3[uu_];
        } else { i0r[islot] = 0.f; i1r[islot] = 0.f; }
    };

    if (MODE == 2) {
        // ---- last iter: only x output (f32) ----
        unpk(2, uload(R0 - 2));
        unpk(3, uload(R0 - 1));
        unpk(0, uload(R0));
        compI(R0 - 1, 1, 3, 0, 2);
        uint2 pu = uload(R0 + 1);
        float pyv, px2;
        {
            int row = R0; bool ok = wok;   // R0 in range always
            int idx = boff + row * WW + w;
            pyv = ok ? y[idx] : 0.f;
            px2 = ok ? cf(x2_in[idx]) : 0.f;
        }
        #pragma unroll
        for (int k = 0; k < HS; ++k) {
            const int rr = R0 + k;
            unpk((k + 1) & 3, pu);
            uint2 nu = uload(rr + 2);
            float yv = pyv, x2v = px2;
            if (k < HS - 1) {
                int row = rr + 1; bool ok = wok;
                int idx = boff + row * WW + w;
                pyv = ok ? y[idx] : 0.f;
                px2 = ok ? cf(x2_in[idx]) : 0.f;
            }
            compI(rr, k & 1, k & 3, (k + 1) & 3, (k + 3) & 3);
            float hD = (rr < HH - 1) ? 1.f : 0.f;
            float i0c = i0r[k & 1], i1c = i1r[k & 1], i1u = i1r[(k + 1) & 1];
            float i0l = SUp(i0c);
            float na = TAUf * (mA * i0l - mB * i0c + i1u - hD * i1c);
            float x = (x2v - na + TAUf * yv) * INV1PT;
            if (cok) xout[boff + rr * WW + w] = x2v + RHOf * (x - x2v);
            pu = nu;
        }
        return;
    }

    // s,t(rr); relax writes on core rows
    auto compS = [&](int rr, int ss_, int isc, int isp,
                     float yv, float x2v, float r20v, float r21v, bool coreRow) {
        if (((unsigned)rr) < (unsigned)HH) {
            if (MODE == 0) {
                sr[ss_] = yv; t0r[ss_] = 0.f; t1r[ss_] = 0.f;
                if (coreRow && cok) {
                    int idx = boff + rr * WW + w;
                    x2_out[idx] = __float2half(yv);
                    *(__half2*)(r2_out + 2 * (size_t)idx) = __floats2half2_rn(0.f, 0.f);
                }
            } else {
                float hD = (rr < HH - 1) ? 1.f : 0.f;
                float i0c = i0r[isc], i1c = i1r[isc], i1u = i1r[isp];
                float i0l = SUp(i0c);
                float na = TAUf * (mA * i0l - mB * i0c + i1u - hD * i1c);
                float x = (x2v - na + TAUf * yv) * INV1PT;
                float rr0 = r20v + TAUf * i0c;
                float rr1 = r21v + TAUf * i1c;
                float mag = sqrtf(rr0 * rr0 + rr1 * rr1) * inv_tl1;
                float rinv = 1.0f / fmaxf(mag, 1.0f);
                float r0 = rr0 - rr0 * rinv;
                float r1 = rr1 - rr1 * rinv;
                sr[ss_]  = 2.f * x  - x2v;
                t0r[ss_] = 2.f * r0 - r20v;
                t1r[ss_] = 2.f * r1 - r21v;
                if (coreRow && cok) {
                    int idx = boff + rr * WW + w;
                    x2_out[idx] = __float2half(x2v + RHOf * (x - x2v));
                    *(__half2*)(r2_out + 2 * (size_t)idx) = __floats2half2_rn(
                        r20v + RHOf * (r0 - r20v), r21v + RHOf * (r1 - r21v));
                }
            }
        } else { sr[ss_] = 0.f; t0r[ss_] = 0.f; t1r[ss_] = 0.f; }
    };

    // u'(ro): sc_=ro&3, sd_=(ro+1)&3, suu=(ro-1)&3, sdd_=(ro+2)&3, uslot=ro&3
    auto compU = [&](int ro, int sc_, int sd_, int suu, int sdd_, int uslot) {
        float hD  = (ro < HH - 1) ? 1.f : 0.f;
        float hD1 = (ro + 1 < HH - 1) ? 1.f : 0.f;
        float sc = sr[sc_], sd = sr[sd_], su = sr[suu], s2 = sr[sdd_];
        float t0c = t0r[sc_], t0u = t0r[suu];
        float t1c = t1r[sc_], t1d = t1r[sd_];
        float sc_p = SD(sc), su_p = SD(su);
        float sc_m = SUp(sc), sd_m = SUp(sd);
        float t0c_m = SUp(t0c), t1c_m = SUp(t1c);
        float v0c = mB * (sc_p - sc) - t0c;
        float v1c = hD * (sd - sc) - t1c;
        float v0u = mB * (su_p - su) - t0u;
        float v0l = (sc - sc_m) - t0c_m;
        float v1l = hD * (sd_m - sc_m) - t1c_m;
        float v1d = hD1 * (s2 - sd) - t1d;
        float G0 = v0c - v0u;
        float G1 = mA * (v0c - v0l);
        float G2 = v1c - mA * v1l;
        float G3 = hD * (v1d - v1c);
        float u0v, u1v, u2v, u3v;
        if (MODE == 0) { u0v = u1v = u2v = u3v = 0.f; }
        else { u0v = uf0[uslot]; u1v = uf1[uslot]; u2v = uf2[uslot]; u3v = uf3[uslot]; }
        float uu0 = u0v + SIGMAf * G0;
        float uu1 = u1v + SIGMAf * G1;
        float uu2 = u2v + SIGMAf * G2;
        float uu3 = u3v + SIGMAf * G3;
        float mag = sqrtf(uu0 * uu0 + uu1 * uu1 + uu2 * uu2 + uu3 * uu3) * inv_l2;
        float ui = 1.0f / fmaxf(mag, 1.0f);
        if (cok) {
            int idx = boff + ro * WW + w;
            __half2 lo = __floats2half2_rn(u0v + RHOf * (uu0 * ui - u0v),
                                           u1v + RHOf * (uu1 * ui - u1v));
            __half2 hi = __floats2half2_rn(u2v + RHOf * (uu2 * ui - u2v),
                                           u3v + RHOf * (uu3 * ui - u3v));
            uint2 st; st.x = *(unsigned*)&lo; st.y = *(unsigned*)&hi;
            *(uint2*)(u_out + 4 * (size_t)idx) = st;
        }
    };

    // ---- prologue ----
    uint2 pu; pu.x = 0u; pu.y = 0u;
    float pyv = 0.f, px2 = 0.f, pr0 = 0.f, pr1 = 0.f;
    if (MODE != 0) {
        unpk(1, uload(R0 - 3));
        unpk(2, uload(R0 - 2));
        unpk(3, uload(R0 - 1));
        compI(R0 - 2, 0, 2, 3, 1);
        pu = uload(R0);
    }
    {
        int row = R0 - 1; bool ok = (((unsigned)row) < (unsigned)HH) && wok;
        int idx = boff + row * WW + w;
        pyv = ok ? y[idx] : 0.f;
        if (MODE == 1) {
            px2 = ok ? cf(x2_in[idx]) : 0.f;
            __half2 rv = ok ? *(const __half2*)(r2_in + 2 * (size_t)idx)
                            : __floats2half2_rn(0.f, 0.f);
            pr0 = __low2float(rv); pr1 = __high2float(rv);
        }
    }

    // ---- main pipeline: rr = R0-1 .. R0+HS+1 ----
    #pragma unroll
    for (int k = 0; k < HS + 3; ++k) {
        const int rr = R0 - 1 + k;
        uint2 nu; nu.x = 0u; nu.y = 0u;
        if (MODE != 0) { unpk(k & 3, pu); nu = uload(rr + 2); }
        float yv = pyv, x2v = px2, r20v = pr0, r21v = pr1;
        if (k < HS + 2) {
            int row = rr + 1; bool ok = (((unsigned)row) < (unsigned)HH) && wok;
            int idx = boff + row * WW + w;
            pyv = ok ? y[idx] : 0.f;
            if (MODE == 1) {
                px2 = ok ? cf(x2_in[idx]) : 0.f;
                __half2 rv = ok ? *(const __half2*)(r2_in + 2 * (size_t)idx)
                                : __floats2half2_rn(0.f, 0.f);
                pr0 = __low2float(rv); pr1 = __high2float(rv);
            }
        }
        if (MODE != 0) compI(rr, (k + 1) & 1, (k + 3) & 3, k & 3, (k + 2) & 3);
        compS(rr, (k + 3) & 3, (k + 1) & 1, k & 1, yv, x2v, r20v, r21v,
              (k >= 1 && k <= HS));
        if (k >= 3) compU(R0 - 3 + k, (k + 1) & 3, (k + 2) & 3, k & 3, (k + 3) & 3,
                          (k + 1) & 3);
        if (MODE != 0) pu = nu;
    }
}

extern "C" void kernel_launch(void* const* d_in, const int* in_sizes, int n_in,
                              void* d_out, int out_size, void* d_ws, size_t ws_size,
                              hipStream_t stream)
{
    const float* y   = (const float*)d_in[0];
    const int*   ths = (const int*)d_in[1];
    __half* ws = (__half*)d_ws;

    __half* Ax2 = ws;
    __half* Ar2 = ws + (size_t)NPIX;
    __half* Au  = ws + (size_t)3 * NPIX;
    __half* Bx2 = ws + (size_t)7 * NPIX;
    __half* Br2 = ws + (size_t)8 * NPIX;
    __half* Bu  = ws + (size_t)10 * NPIX;
    float*  xout = (float*)d_out;

    dim3 block(256);
    dim3 grid(NBLK);

    // iter 0 (analytic) -> B
    sweep<0><<<grid, block, 0, stream>>>(y, ths, Ax2, Ar2, Au, Bx2, Br2, Bu, nullptr);
    // iters 1..8 alternate
    __half *ix2 = Bx2, *ir2 = Br2, *iu = Bu;
    __half *ox2 = Ax2, *or2 = Ar2, *ou = Au;
    for (int it = 1; it <= 8; ++it) {
        sweep<1><<<grid, block, 0, stream>>>(y, ths, ix2, ir2, iu, ox2, or2, ou, nullptr);
        __half* t;
        t = ix2; ix2 = ox2; ox2 = t;
        t = ir2; ir2 = or2; or2 = t;
        t = iu;  iu  = ou;  ou  = t;
    }
    // iter 9: x only -> d_out (state now in ix2/iu)
    sweep<2><<<grid, block, 0, stream>>>(y, ths, ix2, ir2, iu, nullptr, nullptr, nullptr, xout);
}